// Round 1
// baseline (145.511 us; speedup 1.0000x reference)
//
#include <hip/hip_runtime.h>

#define NWIN 4096
#define NTOK 49
#define DIMC 128
#define NHEAD 4
#define HD 32
#define QK_SCALE 0.17677669529663689f  // 32^-0.5

typedef __attribute__((ext_vector_type(8))) short vs8;   // 8 bf16 in 4 VGPRs
typedef __attribute__((ext_vector_type(4))) float vf4;

__device__ __forceinline__ short f2bf(float f) {
  union { float f; unsigned u; } x; x.f = f;
  unsigned r = x.u + 0x7fffu + ((x.u >> 16) & 1u);
  return (short)(r >> 16);
}

// ---------------- prep: weights->bf16, bias table -> padded [4][64][64] ----------------
__global__ void prep_kernel(const float* __restrict__ qkv_w, const float* __restrict__ proj_w,
                            const float* __restrict__ bias_table, const int* __restrict__ rel_index,
                            short* __restrict__ qkv_wb, short* __restrict__ proj_wb,
                            float* __restrict__ bias_pad) {
  int i = blockIdx.x * 256 + threadIdx.x;
  if (i < 49152) qkv_wb[i] = f2bf(qkv_w[i]);
  int j = i - 49152;
  if (j >= 0 && j < 16384) proj_wb[j] = f2bf(proj_w[j]);
  int k = i - 65536;
  if (k >= 0 && k < 16384) {
    int h = k >> 12, rc = k & 4095, r = rc >> 6, c = rc & 63;
    float v = -1e30f;
    if (r < NTOK && c < NTOK) v = bias_table[rel_index[r * NTOK + c] * NHEAD + h];
    bias_pad[k] = v;
  }
}

// ---------------- fused window attention ----------------
// block = 1 window, 256 threads (4 waves); wave w == head w for attention phase.
// LDS (64KB total -> 2 blocks/CU):
//   ldsA: [Qall 16K][Kall 16K][Vt 16K]; Ps[4][64][64]bf16 overlays Qall+Kall after barrier
//   ldsX: Xs[64][128]bf16 -> reused as Os[64][128]bf16
// swizzle: byte_in_row ^= (row&7)<<4  (keeps 16B alignment, kills 256B/128B-stride conflicts)
__launch_bounds__(256, 2)
__global__ void win_attn(const float* __restrict__ x,
                         const float* __restrict__ qkv_b,
                         const float* __restrict__ proj_b,
                         const short* __restrict__ qkv_wb,
                         const short* __restrict__ proj_wb,
                         const float* __restrict__ bias_pad,
                         float* __restrict__ out) {
  __shared__ __align__(16) char ldsA[49152];
  __shared__ __align__(16) char ldsX[16384];

  const int tid  = threadIdx.x;
  const int lane = tid & 63;
  const int w    = tid >> 6;   // wave id 0..3
  const int l15  = lane & 15;
  const int g    = lane >> 4;  // 0..3
  const int win  = blockIdx.x;

  // ---- stage X -> Xs (bf16, swizzled) ----
  const float* xw = x + (size_t)win * (NTOK * DIMC);
#pragma unroll
  for (int it = 0; it < 4; ++it) {
    int chunk = tid + it * 256;          // 0..1023 : row*16 + 16B-chunk
    int row = chunk >> 4;
    int c16 = chunk & 15;
    vs8 v;
    if (row < NTOK) {
      const float* src = xw + row * DIMC + c16 * 8;
      vf4 a = *(const vf4*)(src);
      vf4 b = *(const vf4*)(src + 4);
      v[0] = f2bf(a.x); v[1] = f2bf(a.y); v[2] = f2bf(a.z); v[3] = f2bf(a.w);
      v[4] = f2bf(b.x); v[5] = f2bf(b.y); v[6] = f2bf(b.z); v[7] = f2bf(b.w);
    } else {
#pragma unroll
      for (int q = 0; q < 8; ++q) v[q] = 0;
    }
    *(vs8*)(ldsX + row * 256 + ((c16 * 16) ^ ((row & 7) << 4))) = v;
  }
  __syncthreads();

  // ---- GEMM1: QKV = Xs @ qkv_w^T + qkv_b  (col-split: wave w -> col tiles w, w+4, ...) ----
  vs8 pa[4][4];  // A-fragments [row-tile][k-tile], reused across 6 col tiles
#pragma unroll
  for (int tr = 0; tr < 4; ++tr) {
    int row = tr * 16 + l15;
#pragma unroll
    for (int kk = 0; kk < 4; ++kk)
      pa[tr][kk] = *(const vs8*)(ldsX + row * 256 + ((kk * 64 + g * 16) ^ ((row & 7) << 4)));
  }
#pragma unroll
  for (int ci = 0; ci < 6; ++ci) {
    int c = w + ci * 4;  // col tile 0..23 (cols c*16..c*16+15 of the 384 qkv outputs)
    vs8 bw[4];
    const short* wrow = qkv_wb + (c * 16 + l15) * DIMC;
#pragma unroll
    for (int kk = 0; kk < 4; ++kk) bw[kk] = *(const vs8*)(wrow + kk * 32 + g * 8);
    vf4 acc[4];
#pragma unroll
    for (int tr = 0; tr < 4; ++tr) acc[tr] = (vf4){0.f, 0.f, 0.f, 0.f};
#pragma unroll
    for (int kk = 0; kk < 4; ++kk)
#pragma unroll
      for (int tr = 0; tr < 4; ++tr)
        acc[tr] = __builtin_amdgcn_mfma_f32_16x16x32_bf16(pa[tr][kk], bw[kk], acc[tr], 0, 0, 0);
    int col = c * 16 + l15;
    float bv = qkv_b[col];
#pragma unroll
    for (int tr = 0; tr < 4; ++tr) {
#pragma unroll
      for (int r = 0; r < 4; ++r) {
        int row = tr * 16 + g * 4 + r;  // token
        float v = acc[tr][r] + bv;
        int byte;
        if (col < 128) {        // Q (scale folded in)
          v *= QK_SCALE;
          byte = row * 256 + ((col * 2) ^ ((row & 7) << 4));
        } else if (col < 256) { // K
          int cc = col - 128;
          byte = 16384 + row * 256 + ((cc * 2) ^ ((row & 7) << 4));
        } else {                // V transposed: Vt[dim][token]
          int d = col - 256;
          byte = 32768 + d * 128 + ((row * 2) ^ ((d & 7) << 4));
        }
        *(short*)(ldsA + byte) = f2bf(v);
      }
    }
  }
  __syncthreads();

  // ---- attention: wave w handles head h=w entirely ----
  const int h = w;
  vf4 sacc[4][4];
  vs8 kf[4];
#pragma unroll
  for (int tc = 0; tc < 4; ++tc) {
    int row = tc * 16 + l15;  // key token
    kf[tc] = *(const vs8*)(ldsA + 16384 + row * 256 + ((h * 64 + g * 16) ^ ((row & 7) << 4)));
  }
#pragma unroll
  for (int tr = 0; tr < 4; ++tr) {
    int row = tr * 16 + l15;  // query token
    vs8 qf = *(const vs8*)(ldsA + row * 256 + ((h * 64 + g * 16) ^ ((row & 7) << 4)));
#pragma unroll
    for (int tc = 0; tc < 4; ++tc)
      sacc[tr][tc] = __builtin_amdgcn_mfma_f32_16x16x32_bf16(qf, kf[tc], (vf4){0.f, 0.f, 0.f, 0.f}, 0, 0, 0);
  }
  // bias + masked softmax (rows of S live across the 16 lanes sharing g, 4 tc tiles)
  const float* bp = bias_pad + h * 4096;
#pragma unroll
  for (int tr = 0; tr < 4; ++tr) {
#pragma unroll
    for (int r = 0; r < 4; ++r) {
      int row = tr * 16 + g * 4 + r;
      float v[4];
      float m = -1e38f;
#pragma unroll
      for (int tc = 0; tc < 4; ++tc) {
        v[tc] = sacc[tr][tc][r] + bp[row * 64 + tc * 16 + l15];
        m = fmaxf(m, v[tc]);
      }
      m = fmaxf(m, __shfl_xor(m, 1, 64));
      m = fmaxf(m, __shfl_xor(m, 2, 64));
      m = fmaxf(m, __shfl_xor(m, 4, 64));
      m = fmaxf(m, __shfl_xor(m, 8, 64));
      float s = 0.f;
#pragma unroll
      for (int tc = 0; tc < 4; ++tc) { v[tc] = __expf(v[tc] - m); s += v[tc]; }
      s += __shfl_xor(s, 1, 64);
      s += __shfl_xor(s, 2, 64);
      s += __shfl_xor(s, 4, 64);
      s += __shfl_xor(s, 8, 64);
      float inv = 1.f / s;
#pragma unroll
      for (int tc = 0; tc < 4; ++tc) sacc[tr][tc][r] = v[tc] * inv;
    }
  }
  __syncthreads();  // all waves done reading Q/K -> safe to overlay with P

  // write P (bf16) to Ps[h] (overlays Q/K region)
  char* psBase = ldsA + h * 8192;  // [64][64] bf16, 128B rows, swizzled
#pragma unroll
  for (int tr = 0; tr < 4; ++tr)
#pragma unroll
    for (int r = 0; r < 4; ++r) {
      int row = tr * 16 + g * 4 + r;
#pragma unroll
      for (int tc = 0; tc < 4; ++tc) {
        int col = tc * 16 + l15;
        *(short*)(psBase + row * 128 + ((col * 2) ^ ((row & 7) << 4))) = f2bf(sacc[tr][tc][r]);
      }
    }

  // ---- PV: O_h = P @ V  (V read from transposed Vt, contiguous b128) ----
  vs8 vfr[2][2];  // [kk][tc]
#pragma unroll
  for (int kk = 0; kk < 2; ++kk)
#pragma unroll
    for (int tc = 0; tc < 2; ++tc) {
      int d = h * 32 + tc * 16 + l15;
      vfr[kk][tc] = *(const vs8*)(ldsA + 32768 + d * 128 + (((kk * 32 + g * 8) * 2) ^ ((d & 7) << 4)));
    }
  vf4 oacc[4][2];
#pragma unroll
  for (int tr = 0; tr < 4; ++tr)
#pragma unroll
    for (int tc = 0; tc < 2; ++tc) oacc[tr][tc] = (vf4){0.f, 0.f, 0.f, 0.f};
#pragma unroll
  for (int tr = 0; tr < 4; ++tr) {
    int row = tr * 16 + l15;
#pragma unroll
    for (int kk = 0; kk < 2; ++kk) {
      vs8 pf = *(const vs8*)(psBase + row * 128 + (((kk * 32 + g * 8) * 2) ^ ((row & 7) << 4)));
#pragma unroll
      for (int tc = 0; tc < 2; ++tc)
        oacc[tr][tc] = __builtin_amdgcn_mfma_f32_16x16x32_bf16(pf, vfr[kk][tc], oacc[tr][tc], 0, 0, 0);
    }
  }
  // write O (bf16) into ldsX (Xs is dead)
#pragma unroll
  for (int tr = 0; tr < 4; ++tr)
#pragma unroll
    for (int tc = 0; tc < 2; ++tc)
#pragma unroll
      for (int r = 0; r < 4; ++r) {
        int row = tr * 16 + g * 4 + r;
        int col = h * 32 + tc * 16 + l15;
        *(short*)(ldsX + row * 256 + ((col * 2) ^ ((row & 7) << 4))) = f2bf(oacc[tr][tc][r]);
      }
  __syncthreads();

  // ---- GEMM2: out = O @ proj_w^T + proj_b  (col-split: wave w -> col tiles w, w+4) ----
  vs8 oa[4][4];
#pragma unroll
  for (int tr = 0; tr < 4; ++tr) {
    int row = tr * 16 + l15;
#pragma unroll
    for (int kk = 0; kk < 4; ++kk)
      oa[tr][kk] = *(const vs8*)(ldsX + row * 256 + ((kk * 64 + g * 16) ^ ((row & 7) << 4)));
  }
  float* outw = out + (size_t)win * (NTOK * DIMC);
#pragma unroll
  for (int ci = 0; ci < 2; ++ci) {
    int ct = w + ci * 4;  // col tile 0..7
    vs8 bw[4];
    const short* wrow = proj_wb + (ct * 16 + l15) * DIMC;
#pragma unroll
    for (int kk = 0; kk < 4; ++kk) bw[kk] = *(const vs8*)(wrow + kk * 32 + g * 8);
    vf4 acc[4];
#pragma unroll
    for (int tr = 0; tr < 4; ++tr) acc[tr] = (vf4){0.f, 0.f, 0.f, 0.f};
#pragma unroll
    for (int kk = 0; kk < 4; ++kk)
#pragma unroll
      for (int tr = 0; tr < 4; ++tr)
        acc[tr] = __builtin_amdgcn_mfma_f32_16x16x32_bf16(oa[tr][kk], bw[kk], acc[tr], 0, 0, 0);
    int col = ct * 16 + l15;
    float pb = proj_b[col];
#pragma unroll
    for (int tr = 0; tr < 4; ++tr)
#pragma unroll
      for (int r = 0; r < 4; ++r) {
        int row = tr * 16 + g * 4 + r;
        if (row < NTOK) outw[row * DIMC + col] = acc[tr][r] + pb;
      }
  }
}

extern "C" void kernel_launch(void* const* d_in, const int* in_sizes, int n_in,
                              void* d_out, int out_size, void* d_ws, size_t ws_size,
                              hipStream_t stream) {
  const float* x          = (const float*)d_in[0];
  const float* qkv_w      = (const float*)d_in[1];
  const float* qkv_b      = (const float*)d_in[2];
  const float* proj_w     = (const float*)d_in[3];
  const float* proj_b     = (const float*)d_in[4];
  const float* bias_table = (const float*)d_in[5];
  const int*   rel_index  = (const int*)d_in[6];
  float* out = (float*)d_out;

  short* qkv_wb  = (short*)d_ws;                       // 384*128 bf16 = 98304 B
  short* proj_wb = (short*)((char*)d_ws + 98304);      // 128*128 bf16 = 32768 B
  float* bias_pad = (float*)((char*)d_ws + 131072);    // 4*64*64 f32  = 65536 B

  prep_kernel<<<320, 256, 0, stream>>>(qkv_w, proj_w, bias_table, rel_index,
                                       qkv_wb, proj_wb, bias_pad);
  win_attn<<<NWIN, 256, 0, stream>>>(x, qkv_b, proj_b, qkv_wb, proj_wb, bias_pad, out);
}

// Round 2
// 121.854 us; speedup vs baseline: 1.1941x; 1.1941x over previous
//
#include <hip/hip_runtime.h>

#define NWIN 4096
#define NTOK 49
#define DIMC 128
#define QK_SCALE 0.17677669529663689f  // 32^-0.5

typedef __attribute__((ext_vector_type(8))) short vs8;      // 8 bf16 (4 VGPRs)
typedef __attribute__((ext_vector_type(4))) float vf4;
typedef __attribute__((ext_vector_type(2))) unsigned vu2;   // 2 packed bf16x2

__device__ __forceinline__ unsigned cvtpk(float a, float b) {
  unsigned r;
  asm("v_cvt_pk_bf16_f32 %0, %1, %2" : "=v"(r) : "v"(a), "v"(b));
  return r;
}

__device__ __forceinline__ short f2bf(float f) {
  union { float f; unsigned u; } x; x.f = f;
  unsigned r = x.u + 0x7fffu + ((x.u >> 16) & 1u);
  return (short)(r >> 16);
}

// ---------------- prep: weights->bf16, bias table -> padded [4][64][64] ----------------
__global__ void prep_kernel(const float* __restrict__ qkv_w, const float* __restrict__ proj_w,
                            const float* __restrict__ bias_table, const int* __restrict__ rel_index,
                            short* __restrict__ qkv_wb, short* __restrict__ proj_wb,
                            float* __restrict__ bias_pad) {
  int i = blockIdx.x * 256 + threadIdx.x;
  if (i < 49152) qkv_wb[i] = f2bf(qkv_w[i]);
  int j = i - 49152;
  if (j >= 0 && j < 16384) proj_wb[j] = f2bf(proj_w[j]);
  int k = i - 65536;
  if (k >= 0 && k < 16384) {
    int h = k >> 12, rc = k & 4095, r = rc >> 6, c = rc & 63;
    float v = -1e30f;
    if (r < NTOK && c < NTOK) v = bias_table[rel_index[r * NTOK + c] * 4 + h];
    bias_pad[k] = v;
  }
}

// ---------------- fused window attention ----------------
// block = 1 window, 4 waves; wave w == head w for attention.
// LDS 48KB -> 3 blocks/CU:
//   ldsA[32K]: Q[64][128]bf16 | K[64][128]bf16  ->  Ps[4][64][64]bf16 (overlay)
//   ldsX[16K]: Xs[64][128]bf16 -> Vt[128][64]bf16 -> Os[64][128]bf16
// swizzle: byte_in_row ^= (row&7)<<4
__launch_bounds__(256, 3)
__global__ void win_attn(const float* __restrict__ x,
                         const float* __restrict__ qkv_b,
                         const float* __restrict__ proj_b,
                         const short* __restrict__ qkv_wb,
                         const short* __restrict__ proj_wb,
                         const float* __restrict__ bias_pad,
                         float* __restrict__ out) {
  __shared__ __align__(16) char ldsA[32768];
  __shared__ __align__(16) char ldsX[16384];

  const int tid  = threadIdx.x;
  const int lane = tid & 63;
  const int w    = tid >> 6;
  const int l15  = lane & 15;
  const int g    = lane >> 4;
  const int win  = blockIdx.x;

  // ---- stage X -> Xs (bf16, swizzled) ----
  const float* xw = x + (size_t)win * (NTOK * DIMC);
#pragma unroll
  for (int it = 0; it < 4; ++it) {
    int chunk = tid + it * 256;
    int row = chunk >> 4, c16 = chunk & 15;
    union { vs8 s; unsigned u[4]; } pk;
    if (row < NTOK) {
      const float* src = xw + row * DIMC + c16 * 8;
      vf4 a = *(const vf4*)src;
      vf4 b = *(const vf4*)(src + 4);
      pk.u[0] = cvtpk(a.x, a.y); pk.u[1] = cvtpk(a.z, a.w);
      pk.u[2] = cvtpk(b.x, b.y); pk.u[3] = cvtpk(b.z, b.w);
    } else {
      pk.u[0] = pk.u[1] = pk.u[2] = pk.u[3] = 0u;
    }
    *(vs8*)(ldsX + row * 256 + ((c16 * 16) ^ ((row & 7) << 4))) = pk.s;
  }
  __syncthreads();

  // ---- A-fragments of X (held in regs for whole GEMM1) ----
  vs8 pa[4][4];
#pragma unroll
  for (int tr = 0; tr < 4; ++tr) {
    int row = tr * 16 + l15;
#pragma unroll
    for (int kk = 0; kk < 4; ++kk)
      pa[tr][kk] = *(const vs8*)(ldsX + row * 256 + ((kk * 64 + g * 16) ^ ((row & 7) << 4)));
  }
  __syncthreads();  // Xs dead -> Vt may overlay

  // ---- GEMM1: wave w does col tiles c = w, w+4, ..., w+20 (Q:0-7, K:8-15, V:16-23) ----
#pragma unroll
  for (int ci = 0; ci < 6; ++ci) {
    const int c = w + ci * 4;
    vs8 bw[4];
    const short* wrow = qkv_wb + (c * 16 + l15) * DIMC;
#pragma unroll
    for (int kk = 0; kk < 4; ++kk) bw[kk] = *(const vs8*)(wrow + kk * 32 + g * 8);
    vf4 acc[4];
#pragma unroll
    for (int tr = 0; tr < 4; ++tr) acc[tr] = (vf4){0.f, 0.f, 0.f, 0.f};
    if (ci < 4) {
      // swapped: D[outch][token]; lane: token=tr*16+l15, outch=c*16+g*4+r (contiguous)
#pragma unroll
      for (int kk = 0; kk < 4; ++kk)
#pragma unroll
        for (int tr = 0; tr < 4; ++tr)
          acc[tr] = __builtin_amdgcn_mfma_f32_16x16x32_bf16(bw[kk], pa[tr][kk], acc[tr], 0, 0, 0);
      vf4 qb = *(const vf4*)(qkv_b + c * 16 + g * 4);
      const bool isQ = (ci < 2);
      const float sc = isQ ? QK_SCALE : 1.0f;
      const int base = isQ ? 0 : 16384;
      const int cb = (isQ ? c : c - 8) * 32 + g * 8;  // byte offset of outch*2 in row
#pragma unroll
      for (int tr = 0; tr < 4; ++tr) {
        int token = tr * 16 + l15;
        vu2 p;
        p[0] = cvtpk((acc[tr][0] + qb[0]) * sc, (acc[tr][1] + qb[1]) * sc);
        p[1] = cvtpk((acc[tr][2] + qb[2]) * sc, (acc[tr][3] + qb[3]) * sc);
        *(vu2*)(ldsA + base + token * 256 + (cb ^ ((token & 7) << 4))) = p;
      }
    } else {
      // normal: D[token][outch]; lane: d=(c-16)*16+l15, tokens tr*16+g*4+r (contiguous) -> Vt
#pragma unroll
      for (int kk = 0; kk < 4; ++kk)
#pragma unroll
        for (int tr = 0; tr < 4; ++tr)
          acc[tr] = __builtin_amdgcn_mfma_f32_16x16x32_bf16(pa[tr][kk], bw[kk], acc[tr], 0, 0, 0);
      int d = (c - 16) * 16 + l15;
      float bv = qkv_b[c * 16 + l15];
#pragma unroll
      for (int tr = 0; tr < 4; ++tr) {
        int tb = (tr * 16 + g * 4) * 2;
        vu2 p;
        p[0] = cvtpk(acc[tr][0] + bv, acc[tr][1] + bv);
        p[1] = cvtpk(acc[tr][2] + bv, acc[tr][3] + bv);
        *(vu2*)(ldsX + d * 128 + (tb ^ ((d & 7) << 4))) = p;
      }
    }
  }
  __syncthreads();  // Q,K,Vt ready

  // ---- attention, head h = w:  S^T = K·Q^T ----
  const int h = w;
  vs8 kf[4], qf[4];
#pragma unroll
  for (int t = 0; t < 4; ++t) {
    int r = t * 16 + l15;
    kf[t] = *(const vs8*)(ldsA + 16384 + r * 256 + ((h * 64 + g * 16) ^ ((r & 7) << 4)));
    qf[t] = *(const vs8*)(ldsA + r * 256 + ((h * 64 + g * 16) ^ ((r & 7) << 4)));
  }
  vf4 sacc[4][4];  // [tr][tc]: q = tr*16+l15, key = tc*16+g*4+r
#pragma unroll
  for (int tr = 0; tr < 4; ++tr)
#pragma unroll
    for (int tc = 0; tc < 4; ++tc)
      sacc[tr][tc] = __builtin_amdgcn_mfma_f32_16x16x32_bf16(kf[tc], qf[tr], (vf4){0.f, 0.f, 0.f, 0.f}, 0, 0, 0);

  // ---- softmax: 16 in-lane values per q-row + 2 shfl (16,32); defer 1/s to O ----
  const float* bp = bias_pad + h * 4096;
  float inv[4];
#pragma unroll
  for (int tr = 0; tr < 4; ++tr) {
    int q = tr * 16 + l15;
    float v[4][4];
    float m = -1e38f;
#pragma unroll
    for (int tc = 0; tc < 4; ++tc) {
      vf4 b4 = *(const vf4*)(bp + q * 64 + tc * 16 + g * 4);
#pragma unroll
      for (int r = 0; r < 4; ++r) { v[tc][r] = sacc[tr][tc][r] + b4[r]; m = fmaxf(m, v[tc][r]); }
    }
    m = fmaxf(m, __shfl_xor(m, 16, 64));
    m = fmaxf(m, __shfl_xor(m, 32, 64));
    float s = 0.f;
#pragma unroll
    for (int tc = 0; tc < 4; ++tc)
#pragma unroll
      for (int r = 0; r < 4; ++r) { float e = __expf(v[tc][r] - m); sacc[tr][tc][r] = e; s += e; }
    s += __shfl_xor(s, 16, 64);
    s += __shfl_xor(s, 32, 64);
    inv[tr] = 1.0f / s;
  }
  __syncthreads();  // all waves done reading Q/K -> P may overlay

  // ---- write P (unnormalized exp, row-major [q][key]) ----
  char* ps = ldsA + h * 8192;
#pragma unroll
  for (int tr = 0; tr < 4; ++tr) {
    int q = tr * 16 + l15;
#pragma unroll
    for (int tc = 0; tc < 4; ++tc) {
      vu2 p;
      p[0] = cvtpk(sacc[tr][tc][0], sacc[tr][tc][1]);
      p[1] = cvtpk(sacc[tr][tc][2], sacc[tr][tc][3]);
      *(vu2*)(ps + q * 128 + ((tc * 32 + g * 8) ^ ((q & 7) << 4))) = p;
    }
  }

  // ---- PV (swapped): O^T = Vt·P^T ----
  vs8 vfr[2][2];
#pragma unroll
  for (int kk = 0; kk < 2; ++kk)
#pragma unroll
    for (int tc = 0; tc < 2; ++tc) {
      int d = h * 32 + tc * 16 + l15;
      vfr[kk][tc] = *(const vs8*)(ldsX + d * 128 + (((kk * 32 + g * 8) * 2) ^ ((d & 7) << 4)));
    }
  vf4 oaccT[2][4];  // [tc][tr]: q = tr*16+l15, d = h*32+tc*16+g*4+r
#pragma unroll
  for (int tc = 0; tc < 2; ++tc)
#pragma unroll
    for (int tr = 0; tr < 4; ++tr) oaccT[tc][tr] = (vf4){0.f, 0.f, 0.f, 0.f};
#pragma unroll
  for (int tr = 0; tr < 4; ++tr) {
    int q = tr * 16 + l15;
#pragma unroll
    for (int kk = 0; kk < 2; ++kk) {
      vs8 pf = *(const vs8*)(ps + q * 128 + (((kk * 32 + g * 8) * 2) ^ ((q & 7) << 4)));
#pragma unroll
      for (int tc = 0; tc < 2; ++tc)
        oaccT[tc][tr] = __builtin_amdgcn_mfma_f32_16x16x32_bf16(vfr[kk][tc], pf, oaccT[tc][tr], 0, 0, 0);
    }
  }
  __syncthreads();  // Vt dead -> O may overlay

  // ---- write O (normalized), row-major [q][128] ----
#pragma unroll
  for (int tr = 0; tr < 4; ++tr) {
    int q = tr * 16 + l15;
    float iv = inv[tr];
#pragma unroll
    for (int tc = 0; tc < 2; ++tc) {
      int db = (h * 32 + tc * 16 + g * 4) * 2;
      vu2 p;
      p[0] = cvtpk(oaccT[tc][tr][0] * iv, oaccT[tc][tr][1] * iv);
      p[1] = cvtpk(oaccT[tc][tr][2] * iv, oaccT[tc][tr][3] * iv);
      *(vu2*)(ldsX + q * 256 + (db ^ ((q & 7) << 4))) = p;
    }
  }
  __syncthreads();

  // ---- GEMM2 (swapped): out^T tiles -> float4 stores ----
  vs8 oa[4][4];
#pragma unroll
  for (int tr = 0; tr < 4; ++tr) {
    int row = tr * 16 + l15;
#pragma unroll
    for (int kk = 0; kk < 4; ++kk)
      oa[tr][kk] = *(const vs8*)(ldsX + row * 256 + ((kk * 64 + g * 16) ^ ((row & 7) << 4)));
  }
  float* outw = out + (size_t)win * (NTOK * DIMC);
#pragma unroll
  for (int ci = 0; ci < 2; ++ci) {
    int ct = w + ci * 4;
    vs8 bw2[4];
    const short* wr = proj_wb + (ct * 16 + l15) * DIMC;
#pragma unroll
    for (int kk = 0; kk < 4; ++kk) bw2[kk] = *(const vs8*)(wr + kk * 32 + g * 8);
    vf4 acc[4];
#pragma unroll
    for (int tr = 0; tr < 4; ++tr) acc[tr] = (vf4){0.f, 0.f, 0.f, 0.f};
#pragma unroll
    for (int kk = 0; kk < 4; ++kk)
#pragma unroll
      for (int tr = 0; tr < 4; ++tr)
        acc[tr] = __builtin_amdgcn_mfma_f32_16x16x32_bf16(bw2[kk], oa[tr][kk], acc[tr], 0, 0, 0);
    vf4 pb = *(const vf4*)(proj_b + ct * 16 + g * 4);
#pragma unroll
    for (int tr = 0; tr < 4; ++tr) {
      int token = tr * 16 + l15;
      if (token < NTOK) {
        vf4 o = acc[tr] + pb;
        *(vf4*)(outw + token * DIMC + ct * 16 + g * 4) = o;
      }
    }
  }
}

extern "C" void kernel_launch(void* const* d_in, const int* in_sizes, int n_in,
                              void* d_out, int out_size, void* d_ws, size_t ws_size,
                              hipStream_t stream) {
  const float* x          = (const float*)d_in[0];
  const float* qkv_w      = (const float*)d_in[1];
  const float* qkv_b      = (const float*)d_in[2];
  const float* proj_w     = (const float*)d_in[3];
  const float* proj_b     = (const float*)d_in[4];
  const float* bias_table = (const float*)d_in[5];
  const int*   rel_index  = (const int*)d_in[6];
  float* out = (float*)d_out;

  short* qkv_wb   = (short*)d_ws;                      // 49152 bf16
  short* proj_wb  = (short*)((char*)d_ws + 98304);     // 16384 bf16
  float* bias_pad = (float*)((char*)d_ws + 131072);    // 4*64*64 f32

  prep_kernel<<<320, 256, 0, stream>>>(qkv_w, proj_w, bias_table, rel_index,
                                       qkv_wb, proj_wb, bias_pad);
  win_attn<<<NWIN, 256, 0, stream>>>(x, qkv_b, proj_b, qkv_wb, proj_wb, bias_pad, out);
}